// Round 1
// baseline (776.715 us; speedup 1.0000x reference)
//
#include <hip/hip_runtime.h>
#include <stdint.h>

#define Bb 8
#define Ss 4096
#define Dd 1024
#define Mm (Bb*Ss)      // 32768 rows
#define Nn (2*Dd)       // 2048 cols (Q | K')
#define Kk Dd           // 1024

typedef _Float16 half8 __attribute__((ext_vector_type(8)));
typedef _Float16 half4v __attribute__((ext_vector_type(4)));
typedef float f32x4 __attribute__((ext_vector_type(4)));

#define LO_SCALE 2048.0f
#define INV_LO_SCALE (1.0f/2048.0f)

__device__ __forceinline__ void gld_lds16(const void* g, void* l) {
  __builtin_amdgcn_global_load_lds(
      (const __attribute__((address_space(1))) unsigned int*)g,
      (__attribute__((address_space(3))) unsigned int*)l, 16, 0, 0);
}

// ---------------- K1: fp32 -> fp16 hi/lo split (lo pre-scaled by 2048) -------
__global__ void split_kernel(const float* __restrict__ src,
                             _Float16* __restrict__ hi,
                             _Float16* __restrict__ lo, int n4) {
  int i = blockIdx.x * 256 + threadIdx.x;
  if (i >= n4) return;
  float4 v = ((const float4*)src)[i];
  _Float16 h0 = (_Float16)v.x, h1 = (_Float16)v.y, h2 = (_Float16)v.z, h3 = (_Float16)v.w;
  _Float16 l0 = (_Float16)((v.x - (float)h0) * LO_SCALE);
  _Float16 l1 = (_Float16)((v.y - (float)h1) * LO_SCALE);
  _Float16 l2 = (_Float16)((v.z - (float)h2) * LO_SCALE);
  _Float16 l3 = (_Float16)((v.w - (float)h3) * LO_SCALE);
  ((half4v*)hi)[i] = (half4v){h0, h1, h2, h3};
  ((half4v*)lo)[i] = (half4v){l0, l1, l2, l3};
}

// ---------------- K2: fp16x2 split GEMM, C[m,n] = sum_k A[m,k]*B[n,k] --------
// A = X (hi/lo) [Mm x Kk], B = [Wq;Wk] (hi/lo) [Nn x Kk], C fp32 [Mm x Nn]
__global__ __launch_bounds__(256, 2)
void gemm_split(const _Float16* __restrict__ AhG, const _Float16* __restrict__ AlG,
                const _Float16* __restrict__ BhG, const _Float16* __restrict__ BlG,
                const float* __restrict__ bq, const float* __restrict__ bk,
                float* __restrict__ C) {
  __shared__ __align__(16) _Float16 AsH[128 * 32];
  __shared__ __align__(16) _Float16 AsL[128 * 32];
  __shared__ __align__(16) _Float16 BsH[128 * 32];
  __shared__ __align__(16) _Float16 BsL[128 * 32];

  const int tid  = threadIdx.x;
  const int wave = tid >> 6;
  const int lane = tid & 63;
  const int m0 = blockIdx.y * 128;
  const int n0 = blockIdx.x * 128;
  const int wm = (wave >> 1) * 64;
  const int wn = (wave & 1) * 64;

  f32x4 accH[4][4];
  f32x4 accX[4][4];
#pragma unroll
  for (int i = 0; i < 4; ++i)
#pragma unroll
    for (int j = 0; j < 4; ++j) {
      accH[i][j] = (f32x4){0.f, 0.f, 0.f, 0.f};
      accX[i][j] = (f32x4){0.f, 0.f, 0.f, 0.f};
    }

  // staging: each wave covers rows [wave*32, wave*32+32) of each 128x32 tile,
  // 2 issues of 16 rows; lane -> row wave*32+it*16+lane/4, half-col (lane&3)*8
  const int srow = (lane >> 2);
  const int scol = (lane & 3) * 8;

  for (int kt = 0; kt < Kk / 32; ++kt) {
    const int k0 = kt * 32;
#pragma unroll
    for (int it = 0; it < 2; ++it) {
      const int r = wave * 32 + it * 16 + srow;
      const int ldsbase = (wave * 32 + it * 16) * 32;
      const size_t ga = (size_t)(m0 + r) * Kk + k0 + scol;
      const size_t gb = (size_t)(n0 + r) * Kk + k0 + scol;
      gld_lds16(AhG + ga, &AsH[ldsbase]);
      gld_lds16(AlG + ga, &AsL[ldsbase]);
      gld_lds16(BhG + gb, &BsH[ldsbase]);
      gld_lds16(BlG + gb, &BsL[ldsbase]);
    }
    __syncthreads();

    const int fr = (lane & 15);        // fragment row within 16
    const int fk = (lane >> 4) * 8;    // k offset within 32
    half8 bh[4], bl[4];
#pragma unroll
    for (int j = 0; j < 4; ++j) {
      bh[j] = *(const half8*)&BsH[(wn + 16 * j + fr) * 32 + fk];
      bl[j] = *(const half8*)&BsL[(wn + 16 * j + fr) * 32 + fk];
    }
#pragma unroll
    for (int i = 0; i < 4; ++i) {
      half8 ah = *(const half8*)&AsH[(wm + 16 * i + fr) * 32 + fk];
      half8 al = *(const half8*)&AsL[(wm + 16 * i + fr) * 32 + fk];
#pragma unroll
      for (int j = 0; j < 4; ++j) {
        accH[i][j] = __builtin_amdgcn_mfma_f32_16x16x32_f16(ah, bh[j], accH[i][j], 0, 0, 0);
        accX[i][j] = __builtin_amdgcn_mfma_f32_16x16x32_f16(ah, bl[j], accX[i][j], 0, 0, 0);
        accX[i][j] = __builtin_amdgcn_mfma_f32_16x16x32_f16(al, bh[j], accX[i][j], 0, 0, 0);
      }
    }
    __syncthreads();
  }

  // epilogue: C[m,n] = accH + accX/2048 + bias(n)
  const int quad = (lane >> 4);
#pragma unroll
  for (int j = 0; j < 4; ++j) {
    const int n = n0 + wn + 16 * j + (lane & 15);
    const float bias = (n < Dd) ? bq[n] : bk[n - Dd];
#pragma unroll
    for (int i = 0; i < 4; ++i) {
      const int row0 = m0 + wm + 16 * i + quad * 4;
#pragma unroll
      for (int r = 0; r < 4; ++r) {
        float v = accH[i][j][r] + accX[i][j][r] * INV_LO_SCALE + bias;
        C[(size_t)(row0 + r) * Nn + n] = v;
      }
    }
  }
}

// ---------------- K3: per-row cos/p/b (one wave per row) ---------------------
__global__ void cos_pass(const float* __restrict__ QK,
                         float* __restrict__ p_out, float* __restrict__ b_out) {
  const int s = blockIdx.x * 4 + (threadIdx.x >> 6);
  const int lane = threadIdx.x & 63;
  if (s >= Mm) return;
  if ((s & (Ss - 1)) == 0) {
    if (lane == 0) { p_out[s] = 1.0f; b_out[s] = 1.0f; }
    return;
  }
  const float* qrow = QK + (size_t)s * Nn;            // Q_s   at cols [0,1024)
  const float* krow = QK + (size_t)(s - 1) * Nn + Dd; // K'_{s-1} at cols [1024,2048)
  float dot = 0.f, nq = 0.f, nk = 0.f;
#pragma unroll
  for (int e = lane * 4; e < Dd; e += 256) {
    float4 qv = *(const float4*)&qrow[e];
    float4 kv = *(const float4*)&krow[e];
    dot += qv.x * kv.x + qv.y * kv.y + qv.z * kv.z + qv.w * kv.w;
    nq  += qv.x * qv.x + qv.y * qv.y + qv.z * qv.z + qv.w * qv.w;
    nk  += kv.x * kv.x + kv.y * kv.y + kv.z * kv.z + kv.w * kv.w;
  }
#pragma unroll
  for (int off = 32; off > 0; off >>= 1) {
    dot += __shfl_xor(dot, off);
    nq  += __shfl_xor(nq,  off);
    nk  += __shfl_xor(nk,  off);
  }
  if (lane == 0) {
    float denom = fmaxf(sqrtf(nq), 1e-8f) * fmaxf(sqrtf(nk), 1e-8f);
    float cs = dot / denom;
    float p = 0.5f * (1.0f - cs);
    p_out[s] = p;
    b_out[s] = (p >= 0.5f) ? 1.0f : 0.0f;
  }
}

// ---------------- K4: per-batch stable scan of flags -------------------------
__global__ void scan_flags(const float* __restrict__ b_out,
                           int* __restrict__ sel, int* __restrict__ counts) {
  const int b = blockIdx.x;
  const int tid = threadIdx.x;
  const int lane = tid & 63;
  const int w = tid >> 6;
  __shared__ int wtot[4];
  int running = 0;
  for (int c = 0; c < Ss / 256; ++c) {
    const int i = c * 256 + tid;
    const bool f = b_out[b * Ss + i] != 0.0f;
    unsigned long long m = __ballot(f);
    int pre = __popcll(m & ((1ull << lane) - 1ull));
    if (lane == 0) wtot[w] = __popcll(m);
    __syncthreads();
    int woff = 0;
#pragma unroll
    for (int ww = 0; ww < 4; ++ww)
      if (ww < w) woff += wtot[ww];
    int tot = wtot[0] + wtot[1] + wtot[2] + wtot[3];
    if (f) sel[b * Ss + running + woff + pre] = i;
    running += tot;
    __syncthreads();
  }
  if (tid == 0) counts[b] = running;
}

// ---------------- K5: gather selected rows / zero-fill -----------------------
__global__ void write_out(const float* __restrict__ x, const int* __restrict__ sel,
                          const int* __restrict__ counts, float* __restrict__ out) {
  const int blk = blockIdx.x;       // output row index in [0, Mm)
  const int b = blk >> 12;          // / 4096
  const int r = blk & (Ss - 1);
  const int tid = threadIdx.x;
  float4 v = {0.f, 0.f, 0.f, 0.f};
  if (r < counts[b]) {
    const int src = sel[b * Ss + r];
    v = *(const float4*)&x[((size_t)b * Ss + src) * Dd + tid * 4];
  }
  *(float4*)&out[(size_t)blk * Dd + tid * 4] = v;
}

extern "C" void kernel_launch(void* const* d_in, const int* in_sizes, int n_in,
                              void* d_out, int out_size, void* d_ws, size_t ws_size,
                              hipStream_t stream) {
  const float* x  = (const float*)d_in[0];
  const float* Wq = (const float*)d_in[1];
  const float* bq = (const float*)d_in[2];
  const float* Wk = (const float*)d_in[3];
  const float* bk = (const float*)d_in[4];
  float* out = (float*)d_out;

  // workspace layout
  uint8_t* w = (uint8_t*)d_ws;
  _Float16* XH = (_Float16*)w;             w += (size_t)Mm * Kk * 2;
  _Float16* XL = (_Float16*)w;             w += (size_t)Mm * Kk * 2;
  _Float16* WH = (_Float16*)w;             w += (size_t)Nn * Kk * 2;
  _Float16* WL = (_Float16*)w;             w += (size_t)Nn * Kk * 2;
  float*    QK = (float*)w;                w += (size_t)Mm * Nn * 4;
  int*      sel = (int*)w;                 w += (size_t)Mm * 4;
  int*      counts = (int*)w;              w += 64;

  float* p_out = out + (size_t)Mm * Dd;
  float* b_out = p_out + Mm;

  // K1: splits
  {
    int n4 = Mm * Kk / 4;
    split_kernel<<<n4 / 256, 256, 0, stream>>>(x, XH, XL, n4);
    int w4 = Dd * Dd / 4;
    split_kernel<<<w4 / 256, 256, 0, stream>>>(Wq, WH, WL, w4);
    split_kernel<<<w4 / 256, 256, 0, stream>>>(Wk, WH + (size_t)Dd * Dd, WL + (size_t)Dd * Dd, w4);
  }
  // K2: GEMM
  {
    dim3 grid(Nn / 128, Mm / 128);
    gemm_split<<<grid, 256, 0, stream>>>(XH, XL, WH, WL, bq, bk, QK);
  }
  // K3: cosine/p/b
  cos_pass<<<Mm / 4, 256, 0, stream>>>(QK, p_out, b_out);
  // K4: scan
  scan_flags<<<Bb, 256, 0, stream>>>(b_out, sel, counts);
  // K5: writer
  write_out<<<Mm, 256, 0, stream>>>(x, sel, counts, out);
}